// Round 6
// baseline (95.496 us; speedup 1.0000x reference)
//
#include <hip/hip_runtime.h>
#include <math.h>

typedef __attribute__((ext_vector_type(4))) float f32x4;
typedef __attribute__((ext_vector_type(8))) short bf16x8;

#define NCLS  1000
#define DDIM  128
#define NB    65536
#define K2    14.426950408889634f   /* (1/T)*log2(e): base-2 logits */
#define LN2   0.6931471805599453f

__device__ inline short f2bf(float f) {
  union { float f; unsigned u; } x; x.f = f;
  unsigned r = (x.u + 0x7fffu + ((x.u >> 16) & 1u)) >> 16;  // RNE
  return (short)r;
}
__device__ inline void gll16(const void* g, void* l) {
  __builtin_amdgcn_global_load_lds(
      (const __attribute__((address_space(1))) unsigned int*)g,
      (__attribute__((address_space(3))) unsigned int*)l, 16, 0, 0);
}

// mu (f32 1000x128) -> bf16 FRAG-MAJOR, zero-padded to 1024 classes.
// byte(c,ks,khi) = (c>>7)*32768 + ((c>>4)&7)*4096 + ks*1024 + (khi*16+(c&15))*16
// Each MFMA B-fragment (16 cols x 32 k) is a contiguous lane-linear 1KB.
__global__ __launch_bounds__(256) void prep_mu(const float* __restrict__ mu,
                                               short* __restrict__ mubf) {
  int idx = blockIdx.x * 256 + threadIdx.x;   // 64 blocks -> 16384 16B units
  int c = idx >> 4, j = idx & 15;
  int ks = j >> 2, khi = j & 3;
  bf16x8 o = {0, 0, 0, 0, 0, 0, 0, 0};
  if (c < NCLS) {
    const float4* p = reinterpret_cast<const float4*>(mu + (size_t)c * DDIM + ks * 32 + khi * 8);
    float4 u0 = p[0], u1 = p[1];
    o[0] = f2bf(u0.x); o[1] = f2bf(u0.y); o[2] = f2bf(u0.z); o[3] = f2bf(u0.w);
    o[4] = f2bf(u1.x); o[5] = f2bf(u1.y); o[6] = f2bf(u1.z); o[7] = f2bf(u1.w);
  }
  size_t a16 = (size_t)(c >> 7) * 2048 + ((c >> 4) & 7) * 256 + ks * 64 + khi * 16 + (c & 15);
  *reinterpret_cast<bf16x8*>(mubf + a16 * 8) = o;
}

// Compactness: 512 blocks x 4 waves; wave = 32 rows x all 1024 cols.
// B staged in 4 PHASES of 256 cols (64KB LDS, single buffer). Between the
// 2 barriers of a phase, waves free-run 4x(16 ds_read + 32 MFMA + softmax)
// with no sync -> deep ILP instead of per-chunk lockstep.
__global__ __launch_bounds__(256, 2) void cider_comp(
    const float* __restrict__ z, const short* __restrict__ mubf,
    const int* __restrict__ tgt, float* __restrict__ accum) {
  const int tid = threadIdx.x;
  const int wid = tid >> 6, lane = tid & 63;
  const int lo = lane & 15, hi = lane >> 4;
  const int rowbase = blockIdx.x * 128 + wid * 32;

  __shared__ __align__(16) char Bt[65536];
  const char* mb = (const char*)mubf;

  // stage phase 0 before the register prologue (DMA flies under z loads)
  {
    const char* src = mb + wid * 1024 + lane * 16;
    char* dst = Bt + wid * 1024;
#pragma unroll
    for (int i = 0; i < 16; ++i) gll16(src + i * 4096, dst + i * 4096);
  }

  // A fragments (scaled by K2) and targets
  bf16x8 a[2][4];
#pragma unroll
  for (int rt = 0; rt < 2; ++rt) {
    int row = rowbase + rt * 16 + lo;
    const float4* zp = reinterpret_cast<const float4*>(z + (size_t)row * DDIM);
#pragma unroll
    for (int ks = 0; ks < 4; ++ks) {
      float4 u0 = zp[ks * 8 + hi * 2];
      float4 u1 = zp[ks * 8 + hi * 2 + 1];
      bf16x8 s;
      s[0] = f2bf(u0.x * K2); s[1] = f2bf(u0.y * K2);
      s[2] = f2bf(u0.z * K2); s[3] = f2bf(u0.w * K2);
      s[4] = f2bf(u1.x * K2); s[5] = f2bf(u1.y * K2);
      s[6] = f2bf(u1.z * K2); s[7] = f2bf(u1.w * K2);
      a[rt][ks] = s;
    }
  }
  int t8[2][4];
#pragma unroll
  for (int rt = 0; rt < 2; ++rt)
#pragma unroll
    for (int r = 0; r < 4; ++r) t8[rt][r] = tgt[rowbase + rt * 16 + hi * 4 + r];

  float m2[2][4], s2[2][4], pos[2][4];
#pragma unroll
  for (int rt = 0; rt < 2; ++rt)
#pragma unroll
    for (int r = 0; r < 4; ++r) { m2[rt][r] = -1e30f; s2[rt][r] = 0.f; pos[rt][r] = -3.0e38f; }

#pragma unroll 1
  for (int ph = 0; ph < 4; ++ph) {
    __syncthreads();   // stage(ph) landed (barrier drains vmcnt)

    // ---- free-run: 4 groups x (16 ds_read + 32 MFMA + softmax), no sync ----
#pragma unroll
    for (int g = 0; g < 4; ++g) {
      f32x4 acc[2][4];
#pragma unroll
      for (int rt = 0; rt < 2; ++rt)
#pragma unroll
        for (int f = 0; f < 4; ++f) acc[rt][f] = f32x4{0.f, 0.f, 0.f, 0.f};
#pragma unroll
      for (int ks = 0; ks < 4; ++ks) {
#pragma unroll
        for (int f = 0; f < 4; ++f) {
          bf16x8 b = *reinterpret_cast<const bf16x8*>(
              Bt + (g * 4 + f) * 4096 + ks * 1024 + lane * 16);
          acc[0][f] = __builtin_amdgcn_mfma_f32_16x16x32_bf16(a[0][ks], b, acc[0][f], 0, 0, 0);
          acc[1][f] = __builtin_amdgcn_mfma_f32_16x16x32_bf16(a[1][ks], b, acc[1][f], 0, 0, 0);
        }
      }
      const int colb = ph * 256 + g * 64 + lo;
#pragma unroll
      for (int rt = 0; rt < 2; ++rt)
#pragma unroll
        for (int r = 0; r < 4; ++r) {
          float l0 = acc[rt][0][r], l1 = acc[rt][1][r];
          float l2 = acc[rt][2][r], l3 = acc[rt][3][r];
          int t = t8[rt][r];
          float pp = pos[rt][r];
          pp = (colb == t) ? l0 : pp;
          pp = (colb + 16 == t) ? l1 : pp;
          pp = (colb + 32 == t) ? l2 : pp;
          pp = (colb + 48 == t) ? l3 : pp;
          pos[rt][r] = pp;
          float cm = fmaxf(fmaxf(l0, l1), fmaxf(l2, l3));
          float mo = m2[rt][r], mn = fmaxf(mo, cm);
          s2[rt][r] = s2[rt][r] * __builtin_amdgcn_exp2f(mo - mn)
                    + __builtin_amdgcn_exp2f(l0 - mn) + __builtin_amdgcn_exp2f(l1 - mn)
                    + __builtin_amdgcn_exp2f(l2 - mn) + __builtin_amdgcn_exp2f(l3 - mn);
          m2[rt][r] = mn;
        }
    }

    __syncthreads();   // all waves done reading Bt
    if (ph < 3) {      // stage next 64KB quarter
      const char* src = mb + (ph + 1) * 65536 + wid * 1024 + lane * 16;
      char* dst = Bt + wid * 1024;
#pragma unroll
      for (int i = 0; i < 16; ++i) gll16(src + i * 4096, dst + i * 4096);
    }
  }

  // merge 16 lo-lanes per row; pad correction; sum(pos2 - lse2) per wave
  float vsum = 0.f;
#pragma unroll
  for (int rt = 0; rt < 2; ++rt)
#pragma unroll
    for (int r = 0; r < 4; ++r) {
      float m = m2[rt][r], s = s2[rt][r], pp = pos[rt][r];
#pragma unroll
      for (int w = 1; w < 16; w <<= 1) {
        float mo = __shfl_xor(m, w), so = __shfl_xor(s, w);
        float mn = fmaxf(m, mo);
        s = s * __builtin_amdgcn_exp2f(m - mn) + so * __builtin_amdgcn_exp2f(mo - mn);
        m = mn;
        pp = fmaxf(pp, __shfl_xor(pp, w));
      }
      if (lo == 0) {
        s -= 24.0f * __builtin_amdgcn_exp2f(0.0f - m);  // 24 pad cols, logit2==0
        s = fmaxf(s, 1e-30f);
        float lse2 = m + __builtin_amdgcn_logf(s);      // v_log_f32 = log2
        vsum += pp - lse2;
      }
    }
#pragma unroll
  for (int w = 1; w < 64; w <<= 1) vsum += __shfl_xor(vsum, w);
  if (lane == 0) atomicAdd(&accum[0], vsum);
}

// Dispersion: 256 blocks x 1 wave; (row-tile rt, col-quarter q); frag-major L2 reads.
__global__ __launch_bounds__(64) void cider_disp(const short* __restrict__ mubf,
                                                 float2* __restrict__ dpart) {
  const int lane = threadIdx.x;
  const int lo = lane & 15, hi = lane >> 4;
  const int rt = blockIdx.x >> 2, q = blockIdx.x & 3;
  const char* mb = (const char*)mubf;

  bf16x8 a[4];
#pragma unroll
  for (int ks = 0; ks < 4; ++ks)
    a[ks] = *reinterpret_cast<const bf16x8*>(
        mb + (size_t)(rt >> 3) * 32768 + (rt & 7) * 4096 + ks * 1024 + lane * 16);

  int rowg[4];
#pragma unroll
  for (int r = 0; r < 4; ++r) rowg[r] = rt * 16 + hi * 4 + r;

  float m2[4], s2[4];
#pragma unroll
  for (int r = 0; r < 4; ++r) { m2[r] = -1e30f; s2[r] = 0.f; }

#pragma unroll 1
  for (int cc = 0; cc < 4; ++cc) {
    const int c0 = q * 256 + cc * 64;
    f32x4 acc[4];
#pragma unroll
    for (int f = 0; f < 4; ++f) acc[f] = f32x4{0.f, 0.f, 0.f, 0.f};
#pragma unroll
    for (int ks = 0; ks < 4; ++ks) {
#pragma unroll
      for (int f = 0; f < 4; ++f) {
        int Tb = (c0 >> 4) + f;
        bf16x8 b = *reinterpret_cast<const bf16x8*>(
            mb + (size_t)(Tb >> 3) * 32768 + (Tb & 7) * 4096 + ks * 1024 + lane * 16);
        acc[f] = __builtin_amdgcn_mfma_f32_16x16x32_bf16(a[ks], b, acc[f], 0, 0, 0);
      }
    }
#pragma unroll
    for (int r = 0; r < 4; ++r) {
      float l[4];
#pragma unroll
      for (int f = 0; f < 4; ++f) {
        int c = c0 + f * 16 + lo;
        l[f] = (c >= NCLS || c == rowg[r]) ? -1e30f : acc[f][r] * K2;
      }
      float cm = fmaxf(fmaxf(l[0], l[1]), fmaxf(l[2], l[3]));
      float mo = m2[r], mn = fmaxf(mo, cm);
      s2[r] = s2[r] * __builtin_amdgcn_exp2f(mo - mn)
            + __builtin_amdgcn_exp2f(l[0] - mn) + __builtin_amdgcn_exp2f(l[1] - mn)
            + __builtin_amdgcn_exp2f(l[2] - mn) + __builtin_amdgcn_exp2f(l[3] - mn);
      m2[r] = mn;
    }
  }

#pragma unroll
  for (int r = 0; r < 4; ++r) {
    float m = m2[r], s = s2[r];
#pragma unroll
    for (int w = 1; w < 16; w <<= 1) {
      float mo = __shfl_xor(m, w), so = __shfl_xor(s, w);
      float mn = fmaxf(m, mo);
      s = s * __builtin_amdgcn_exp2f(m - mn) + so * __builtin_amdgcn_exp2f(mo - mn);
      m = mn;
    }
    if (lo == 0) dpart[q * 1024 + rt * 16 + hi * 4 + r] = make_float2(m, s);
  }
}

// Final: merge disp quarters + combine losses. One block, 1024 threads.
__global__ __launch_bounds__(1024) void finalize_k(const float* __restrict__ accum,
                                                   const float2* __restrict__ dpart,
                                                   float* __restrict__ out) {
  __shared__ float red[16];
  const int row = threadIdx.x;
  float m = -1e30f, s = 0.f;
#pragma unroll
  for (int qq = 0; qq < 4; ++qq) {
    float2 p = dpart[qq * 1024 + row];
    float mn = fmaxf(m, p.x);
    s = s * __builtin_amdgcn_exp2f(m - mn) + p.y * __builtin_amdgcn_exp2f(p.x - mn);
    m = mn;
  }
  float v = 0.f;
  if (row < NCLS) v = m + __builtin_amdgcn_logf(fmaxf(s, 1e-30f));
#pragma unroll
  for (int w = 1; w < 64; w <<= 1) v += __shfl_xor(v, w);
  if ((row & 63) == 0) red[row >> 6] = v;
  __syncthreads();
  if (row == 0) {
    float t = 0.f;
#pragma unroll
    for (int i = 0; i < 16; ++i) t += red[i];
    float loss_comp = -(LN2 * accum[0] / (float)NB);
    float loss_dis = logf(1.0f / (float)(NCLS - 1)) + LN2 * t / (float)NCLS;
    out[0] = loss_dis + 2.0f * loss_comp;
  }
}

extern "C" void kernel_launch(void* const* d_in, const int* in_sizes, int n_in,
                              void* d_out, int out_size, void* d_ws, size_t ws_size,
                              hipStream_t stream) {
  const float* z = (const float*)d_in[0];
  const int* tgt = (const int*)d_in[1];
  const float* mu = (const float*)d_in[2];
  float* out = (float*)d_out;
  char* ws = (char*)d_ws;
  float*  accum = (float*)ws;                      // 256 B
  short*  mubf  = (short*)(ws + 256);              // 256 KB frag-major
  float2* dpart = (float2*)(ws + 256 + 262144);    // 32 KB

  hipMemsetAsync(d_ws, 0, 256, stream);
  prep_mu<<<dim3(64), dim3(256), 0, stream>>>(mu, mubf);
  cider_comp<<<dim3(512), dim3(256), 0, stream>>>(z, mubf, tgt, accum);
  cider_disp<<<dim3(256), dim3(64), 0, stream>>>(mubf, dpart);
  finalize_k<<<dim3(1), dim3(1024), 0, stream>>>(accum, dpart, out);
}

// Round 7
// 71.663 us; speedup vs baseline: 1.3326x; 1.3326x over previous
//
#include <hip/hip_runtime.h>
#include <math.h>

typedef __attribute__((ext_vector_type(4))) float f32x4;
typedef __attribute__((ext_vector_type(8))) short bf16x8;

#define NCLS  1000
#define DDIM  128
#define NB    65536
#define K2    14.426950408889634f   /* (1/T)*log2(e): base-2 logits */
#define LN2   0.6931471805599453f

__device__ inline short f2bf(float f) {
  union { float f; unsigned u; } x; x.f = f;
  unsigned r = (x.u + 0x7fffu + ((x.u >> 16) & 1u)) >> 16;  // RNE
  return (short)r;
}
__device__ inline float bf2f(short b) {
  union { unsigned u; float f; } x; x.u = ((unsigned)(unsigned short)b) << 16;
  return x.f;
}

// mu (f32 1000x128) -> bf16 FRAG-MAJOR, zero-padded to 1024 classes.
// byte(c,ks,khi) = (c>>7)*32768 + ((c>>4)&7)*4096 + ks*1024 + (khi*16+(c&15))*16
// Each MFMA B-fragment (16 cols x 32 k) is a contiguous lane-linear 1KB.
__global__ __launch_bounds__(256) void prep_mu(const float* __restrict__ mu,
                                               short* __restrict__ mubf) {
  int idx = blockIdx.x * 256 + threadIdx.x;   // 64 blocks -> 16384 16B units
  int c = idx >> 4, j = idx & 15;
  int ks = j >> 2, khi = j & 3;
  bf16x8 o = {0, 0, 0, 0, 0, 0, 0, 0};
  if (c < NCLS) {
    const float4* p = reinterpret_cast<const float4*>(mu + (size_t)c * DDIM + ks * 32 + khi * 8);
    float4 u0 = p[0], u1 = p[1];
    o[0] = f2bf(u0.x); o[1] = f2bf(u0.y); o[2] = f2bf(u0.z); o[3] = f2bf(u0.w);
    o[4] = f2bf(u1.x); o[5] = f2bf(u1.y); o[6] = f2bf(u1.z); o[7] = f2bf(u1.w);
  }
  size_t a16 = (size_t)(c >> 7) * 2048 + ((c >> 4) & 7) * 256 + ks * 64 + khi * 16 + (c & 15);
  *reinterpret_cast<bf16x8*>(mubf + a16 * 8) = o;
}

// Fused main kernel, 528 blocks x 4 waves. NO LDS, NO BARRIERS: B-fragments
// stream straight from L2 (mubf = 256KB, L2-resident per XCD). Blocks <512:
// compactness (wave = 32 rows x 1024 cols). Blocks 512..527: dispersion
// (wave = 16 rows x 1024 cols), runs concurrently.
__global__ __launch_bounds__(256, 2) void cider_main(
    const float* __restrict__ z, const short* __restrict__ mubf,
    const int* __restrict__ tgt, float* __restrict__ accum) {
  const int tid = threadIdx.x;
  const int wid = tid >> 6, lane = tid & 63;
  const int lo = lane & 15, hi = lane >> 4;
  const char* mb = (const char*)mubf;

  if (blockIdx.x < 512) {
    // ================= compactness =================
    const int rowbase = blockIdx.x * 128 + wid * 32;

    bf16x8 a[2][4];
    float pd[2];
#pragma unroll
    for (int rt = 0; rt < 2; ++rt) {
      int row = rowbase + rt * 16 + lo;
      const float4* zp = reinterpret_cast<const float4*>(z + (size_t)row * DDIM);
#pragma unroll
      for (int ks = 0; ks < 4; ++ks) {
        float4 u0 = zp[ks * 8 + hi * 2];
        float4 u1 = zp[ks * 8 + hi * 2 + 1];
        bf16x8 s;
        s[0] = f2bf(u0.x * K2); s[1] = f2bf(u0.y * K2);
        s[2] = f2bf(u0.z * K2); s[3] = f2bf(u0.w * K2);
        s[4] = f2bf(u1.x * K2); s[5] = f2bf(u1.y * K2);
        s[6] = f2bf(u1.z * K2); s[7] = f2bf(u1.w * K2);
        a[rt][ks] = s;
      }
      // pos2 via register dot against frag-major mu[t]
      int t = tgt[row];
      const char* tp = mb + (size_t)(t >> 7) * 32768 + ((t >> 4) & 7) * 4096 + (t & 15) * 16;
      float ad = 0.f;
#pragma unroll
      for (int ks = 0; ks < 4; ++ks) {
        bf16x8 mv = *reinterpret_cast<const bf16x8*>(tp + ks * 1024 + hi * 256);
#pragma unroll
        for (int e = 0; e < 8; ++e) ad += bf2f(a[rt][ks][e]) * bf2f(mv[e]);
      }
      ad += __shfl_xor(ad, 16);
      ad += __shfl_xor(ad, 32);
      pd[rt] = ad;   // pos2 for row(lo), all hi
    }

    float m2[2][4], s2[2][4];
#pragma unroll
    for (int rt = 0; rt < 2; ++rt)
#pragma unroll
      for (int r = 0; r < 4; ++r) { m2[rt][r] = -1e30f; s2[rt][r] = 0.f; }

#pragma unroll 1
    for (int g = 0; g < 16; ++g) {   // 64 cols per iter, straight from L2
      const char* gp = mb + g * 16384 + lane * 16;
      f32x4 acc[2][4];
#pragma unroll
      for (int rt = 0; rt < 2; ++rt)
#pragma unroll
        for (int f = 0; f < 4; ++f) acc[rt][f] = f32x4{0.f, 0.f, 0.f, 0.f};
#pragma unroll
      for (int f = 0; f < 4; ++f) {
        bf16x8 bq[4];
#pragma unroll
        for (int ks = 0; ks < 4; ++ks)
          bq[ks] = *reinterpret_cast<const bf16x8*>(gp + f * 4096 + ks * 1024);
#pragma unroll
        for (int ks = 0; ks < 4; ++ks) {
          acc[0][f] = __builtin_amdgcn_mfma_f32_16x16x32_bf16(a[0][ks], bq[ks], acc[0][f], 0, 0, 0);
          acc[1][f] = __builtin_amdgcn_mfma_f32_16x16x32_bf16(a[1][ks], bq[ks], acc[1][f], 0, 0, 0);
        }
      }
#pragma unroll
      for (int rt = 0; rt < 2; ++rt)
#pragma unroll
        for (int r = 0; r < 4; ++r) {
          float l0 = acc[rt][0][r], l1 = acc[rt][1][r];
          float l2 = acc[rt][2][r], l3 = acc[rt][3][r];
          float cm = fmaxf(fmaxf(l0, l1), fmaxf(l2, l3));
          float mo = m2[rt][r], mn = fmaxf(mo, cm);
          s2[rt][r] = s2[rt][r] * __builtin_amdgcn_exp2f(mo - mn)
                    + __builtin_amdgcn_exp2f(l0 - mn) + __builtin_amdgcn_exp2f(l1 - mn)
                    + __builtin_amdgcn_exp2f(l2 - mn) + __builtin_amdgcn_exp2f(l3 - mn);
          m2[rt][r] = mn;
        }
    }

    float vsum = 0.f;
#pragma unroll
    for (int rt = 0; rt < 2; ++rt)
#pragma unroll
      for (int r = 0; r < 4; ++r) {
        float m = m2[rt][r], s = s2[rt][r];
#pragma unroll
        for (int w = 1; w < 16; w <<= 1) {
          float mo = __shfl_xor(m, w), so = __shfl_xor(s, w);
          float mn = fmaxf(m, mo);
          s = s * __builtin_amdgcn_exp2f(m - mn) + so * __builtin_amdgcn_exp2f(mo - mn);
          m = mn;
        }
        float posv = __shfl(pd[rt], hi * 4 + r);
        if (lo == 0) {
          s -= 24.0f * __builtin_amdgcn_exp2f(0.0f - m);  // 24 pad cols, logit2==0
          s = fmaxf(s, 1e-30f);
          float lse2 = m + __builtin_amdgcn_logf(s);      // v_log_f32 = log2
          vsum += posv - lse2;
        }
      }
#pragma unroll
    for (int w = 1; w < 64; w <<= 1) vsum += __shfl_xor(vsum, w);
    if (lane == 0) atomicAdd(&accum[0], vsum);

  } else {
    // ================= dispersion =================
    const int rbase = (blockIdx.x - 512) * 64 + wid * 16;
    const int Tb = rbase >> 4;

    bf16x8 a[4];
#pragma unroll
    for (int ks = 0; ks < 4; ++ks) {
      bf16x8 raw = *reinterpret_cast<const bf16x8*>(
          mb + (size_t)(Tb >> 3) * 32768 + (Tb & 7) * 4096 + ks * 1024 + lane * 16);
      bf16x8 s;
#pragma unroll
      for (int e = 0; e < 8; ++e) s[e] = f2bf(bf2f(raw[e]) * K2);
      a[ks] = s;
    }
    int rowg[4];
#pragma unroll
    for (int r = 0; r < 4; ++r) rowg[r] = rbase + hi * 4 + r;

    float m2[4], s2[4];
#pragma unroll
    for (int r = 0; r < 4; ++r) { m2[r] = -1e30f; s2[r] = 0.f; }

#pragma unroll 1
    for (int g = 0; g < 16; ++g) {
      const char* gp = mb + g * 16384 + lane * 16;
      f32x4 acc[4];
#pragma unroll
      for (int f = 0; f < 4; ++f) acc[f] = f32x4{0.f, 0.f, 0.f, 0.f};
#pragma unroll
      for (int f = 0; f < 4; ++f) {
        bf16x8 bq[4];
#pragma unroll
        for (int ks = 0; ks < 4; ++ks)
          bq[ks] = *reinterpret_cast<const bf16x8*>(gp + f * 4096 + ks * 1024);
#pragma unroll
        for (int ks = 0; ks < 4; ++ks)
          acc[f] = __builtin_amdgcn_mfma_f32_16x16x32_bf16(a[ks], bq[ks], acc[f], 0, 0, 0);
      }
#pragma unroll
      for (int r = 0; r < 4; ++r) {
        float l[4];
#pragma unroll
        for (int f = 0; f < 4; ++f) {
          int c = g * 64 + f * 16 + lo;
          l[f] = (c >= NCLS || c == rowg[r]) ? -1e30f : acc[f][r];
        }
        float cm = fmaxf(fmaxf(l[0], l[1]), fmaxf(l[2], l[3]));
        float mo = m2[r], mn = fmaxf(mo, cm);
        s2[r] = s2[r] * __builtin_amdgcn_exp2f(mo - mn)
              + __builtin_amdgcn_exp2f(l[0] - mn) + __builtin_amdgcn_exp2f(l[1] - mn)
              + __builtin_amdgcn_exp2f(l[2] - mn) + __builtin_amdgcn_exp2f(l[3] - mn);
        m2[r] = mn;
      }
    }

    float vsum = 0.f;
#pragma unroll
    for (int r = 0; r < 4; ++r) {
      float m = m2[r], s = s2[r];
#pragma unroll
      for (int w = 1; w < 16; w <<= 1) {
        float mo = __shfl_xor(m, w), so = __shfl_xor(s, w);
        float mn = fmaxf(m, mo);
        s = s * __builtin_amdgcn_exp2f(m - mn) + so * __builtin_amdgcn_exp2f(mo - mn);
        m = mn;
      }
      if (lo == 0 && rowg[r] < NCLS)
        vsum += m + __builtin_amdgcn_logf(fmaxf(s, 1e-30f));
    }
#pragma unroll
    for (int w = 1; w < 64; w <<= 1) vsum += __shfl_xor(vsum, w);
    if (lane == 0) atomicAdd(&accum[1], vsum);
  }
}

__global__ void finalize_k(const float* __restrict__ accum, float* __restrict__ out) {
  float loss_comp = -(LN2 * accum[0] / (float)NB);
  float loss_dis = logf(1.0f / (float)(NCLS - 1)) + LN2 * accum[1] / (float)NCLS;
  out[0] = loss_dis + 2.0f * loss_comp;
}

extern "C" void kernel_launch(void* const* d_in, const int* in_sizes, int n_in,
                              void* d_out, int out_size, void* d_ws, size_t ws_size,
                              hipStream_t stream) {
  const float* z = (const float*)d_in[0];
  const int* tgt = (const int*)d_in[1];
  const float* mu = (const float*)d_in[2];
  float* out = (float*)d_out;
  char* ws = (char*)d_ws;
  float* accum = (float*)ws;            // 256 B
  short* mubf  = (short*)(ws + 256);    // 256 KB frag-major

  hipMemsetAsync(d_ws, 0, 256, stream);
  prep_mu<<<dim3(64), dim3(256), 0, stream>>>(mu, mubf);
  cider_main<<<dim3(528), dim3(256), 0, stream>>>(z, mubf, tgt, accum);
  finalize_k<<<dim3(1), dim3(1), 0, stream>>>(accum, out);
}

// Round 10
// 46.420 us; speedup vs baseline: 2.0572x; 1.5438x over previous
//
#include <hip/hip_runtime.h>
#include <math.h>

typedef __attribute__((ext_vector_type(4))) float f32x4;
typedef __attribute__((ext_vector_type(8))) short bf16x8;

#define NCLS  1000
#define DDIM  128
#define NB    65536
#define K2    14.426950408889634f   /* (1/T)*log2(e): base-2 logits */
#define LN2   0.6931471805599453f

__device__ inline short f2bf(float f) {
  union { float f; unsigned u; } x; x.f = f;
  unsigned r = (x.u + 0x7fffu + ((x.u >> 16) & 1u)) >> 16;  // RNE
  return (short)r;
}
__device__ inline float bf2f(short b) {
  union { unsigned u; float f; } x; x.u = ((unsigned)(unsigned short)b) << 16;
  return x.f;
}
__device__ inline void gll16(const void* g, void* l) {
  __builtin_amdgcn_global_load_lds(
      (const __attribute__((address_space(1))) unsigned int*)g,
      (__attribute__((address_space(3))) unsigned int*)l, 16, 0, 0);
}

// mu (f32 1000x128) -> bf16 FRAG-MAJOR, zero-padded to 1024 classes.
// byte(c,ks,khi) = (c>>7)*32768 + ((c>>4)&7)*4096 + ks*1024 + (khi*16+(c&15))*16
// Also zeroes the accumulators (replaces a memset launch).
__global__ __launch_bounds__(256) void prep_mu(const float* __restrict__ mu,
                                               short* __restrict__ mubf,
                                               float* __restrict__ accum) {
  if (blockIdx.x == 0 && threadIdx.x < 8) accum[threadIdx.x] = 0.f;
  int idx = blockIdx.x * 256 + threadIdx.x;   // 64 blocks -> 16384 16B units
  int c = idx >> 4, j = idx & 15;
  int ks = j >> 2, khi = j & 3;
  bf16x8 o = {0, 0, 0, 0, 0, 0, 0, 0};
  if (c < NCLS) {
    const float4* p = reinterpret_cast<const float4*>(mu + (size_t)c * DDIM + ks * 32 + khi * 8);
    float4 u0 = p[0], u1 = p[1];
    o[0] = f2bf(u0.x); o[1] = f2bf(u0.y); o[2] = f2bf(u0.z); o[3] = f2bf(u0.w);
    o[4] = f2bf(u1.x); o[5] = f2bf(u1.y); o[6] = f2bf(u1.z); o[7] = f2bf(u1.w);
  }
  size_t a16 = (size_t)(c >> 7) * 2048 + ((c >> 4) & 7) * 256 + ks * 64 + khi * 16 + (c & 15);
  *reinterpret_cast<bf16x8*>(mubf + a16 * 8) = o;
}

// ONE kernel, grid 320 x 512 threads (8 waves):
//  blocks 0..63   : dispersion (16 mu-rows each; wave wid owns col-eighth)
//  blocks 64..319 : compactness (256 z-rows each = 8 waves x 32 rows).
// Comp: B staged per-block in LDS (2x32KB dbuf, 8 phases, 1 barrier/phase),
// chunk order rotated by block to kill L2 same-line hot-spotting.
// L2 B-traffic: 256x256KB = 67MB (vs 536MB round 7).
__global__ __launch_bounds__(512, 2) void cider_main(
    const float* __restrict__ z, const short* __restrict__ mubf,
    const int* __restrict__ tgt, float* __restrict__ accum) {
  __shared__ __align__(16) char Bt[2][32768];
  __shared__ float red[8];
  __shared__ float dm[8][16], dsv[8][16];

  const int tid = threadIdx.x;
  const int wid = tid >> 6, lane = tid & 63;
  const int lo = lane & 15, hi = lane >> 4;
  const char* mb = (const char*)mubf;

  if (blockIdx.x >= 64) {
    // ======================= compactness =======================
    const int b = blockIdx.x - 64;
    const int rowbase = b * 256 + wid * 32;
    const int rot = b & 7;

    {  // stage phase 0 (chunk rot) into buf 0 — flies under the prologue
      const char* src = mb + rot * 32768 + tid * 16;
      char* dst = &Bt[0][0] + tid * 16;
#pragma unroll
      for (int i = 0; i < 4; ++i) gll16(src + i * 8192, dst + i * 8192);
    }

    // A fragments (scaled by K2) + pos via register dot
    bf16x8 a[2][4];
    float pd[2];
#pragma unroll
    for (int rt = 0; rt < 2; ++rt) {
      int row = rowbase + rt * 16 + lo;
      const float4* zp = reinterpret_cast<const float4*>(z + (size_t)row * DDIM);
#pragma unroll
      for (int ks = 0; ks < 4; ++ks) {
        float4 u0 = zp[ks * 8 + hi * 2];
        float4 u1 = zp[ks * 8 + hi * 2 + 1];
        bf16x8 s;
        s[0] = f2bf(u0.x * K2); s[1] = f2bf(u0.y * K2);
        s[2] = f2bf(u0.z * K2); s[3] = f2bf(u0.w * K2);
        s[4] = f2bf(u1.x * K2); s[5] = f2bf(u1.y * K2);
        s[6] = f2bf(u1.z * K2); s[7] = f2bf(u1.w * K2);
        a[rt][ks] = s;
      }
      int t = tgt[row];
      const char* tp = mb + (size_t)(t >> 7) * 32768 + ((t >> 4) & 7) * 4096 + (t & 15) * 16;
      float ad = 0.f;
#pragma unroll
      for (int ks = 0; ks < 4; ++ks) {
        bf16x8 mv = *reinterpret_cast<const bf16x8*>(tp + ks * 1024 + hi * 256);
#pragma unroll
        for (int e = 0; e < 8; ++e) ad += bf2f(a[rt][ks][e]) * bf2f(mv[e]);
      }
      ad += __shfl_xor(ad, 16);
      ad += __shfl_xor(ad, 32);
      pd[rt] = ad;
    }

    float m2[2][4], s2[2][4];
#pragma unroll
    for (int rt = 0; rt < 2; ++rt)
#pragma unroll
      for (int r = 0; r < 4; ++r) { m2[rt][r] = -1e30f; s2[rt][r] = 0.f; }

#pragma unroll 1
    for (int p = 0; p < 8; ++p) {
      __syncthreads();   // stage(p) landed (barrier drains vmcnt); other buf free
      if (p < 7) {       // issue next 32KB chunk; consumed after the next barrier
        const char* src = mb + ((rot + p + 1) & 7) * 32768 + tid * 16;
        char* dst = &Bt[(p + 1) & 1][0] + tid * 16;
#pragma unroll
        for (int i = 0; i < 4; ++i) gll16(src + i * 8192, dst + i * 8192);
      }
      const char* bp = &Bt[p & 1][0];
#pragma unroll
      for (int gg = 0; gg < 2; ++gg) {
        f32x4 acc[2][4];
#pragma unroll
        for (int rt = 0; rt < 2; ++rt)
#pragma unroll
          for (int f = 0; f < 4; ++f) acc[rt][f] = f32x4{0.f, 0.f, 0.f, 0.f};
#pragma unroll
        for (int f = 0; f < 4; ++f) {
          bf16x8 bq[4];
#pragma unroll
          for (int ks = 0; ks < 4; ++ks)
            bq[ks] = *reinterpret_cast<const bf16x8*>(
                bp + gg * 16384 + f * 4096 + ks * 1024 + lane * 16);
#pragma unroll
          for (int ks = 0; ks < 4; ++ks) {
            acc[0][f] = __builtin_amdgcn_mfma_f32_16x16x32_bf16(a[0][ks], bq[ks], acc[0][f], 0, 0, 0);
            acc[1][f] = __builtin_amdgcn_mfma_f32_16x16x32_bf16(a[1][ks], bq[ks], acc[1][f], 0, 0, 0);
          }
        }
#pragma unroll
        for (int rt = 0; rt < 2; ++rt)
#pragma unroll
          for (int r = 0; r < 4; ++r) {
            float l0 = acc[rt][0][r], l1 = acc[rt][1][r];
            float l2 = acc[rt][2][r], l3 = acc[rt][3][r];
            float cm = fmaxf(fmaxf(l0, l1), fmaxf(l2, l3));
            float mo = m2[rt][r], mn = fmaxf(mo, cm);
            s2[rt][r] = s2[rt][r] * __builtin_amdgcn_exp2f(mo - mn)
                      + __builtin_amdgcn_exp2f(l0 - mn) + __builtin_amdgcn_exp2f(l1 - mn)
                      + __builtin_amdgcn_exp2f(l2 - mn) + __builtin_amdgcn_exp2f(l3 - mn);
            m2[rt][r] = mn;
          }
      }
    }

    // merge 16 lo-lanes per row; pad correction; per-wave sum(pos2 - lse2)
    float vsum = 0.f;
#pragma unroll
    for (int rt = 0; rt < 2; ++rt)
#pragma unroll
      for (int r = 0; r < 4; ++r) {
        float m = m2[rt][r], s = s2[rt][r];
#pragma unroll
        for (int w = 1; w < 16; w <<= 1) {
          float mo = __shfl_xor(m, w), so = __shfl_xor(s, w);
          float mn = fmaxf(m, mo);
          s = s * __builtin_amdgcn_exp2f(m - mn) + so * __builtin_amdgcn_exp2f(mo - mn);
          m = mn;
        }
        float posv = __shfl(pd[rt], hi * 4 + r);
        if (lo == 0) {
          s -= 24.0f * __builtin_amdgcn_exp2f(0.0f - m);  // 24 pad cols, logit2==0
          s = fmaxf(s, 1e-30f);
          float lse2 = m + __builtin_amdgcn_logf(s);      // v_log_f32 = log2
          vsum += posv - lse2;
        }
      }
#pragma unroll
    for (int w = 1; w < 64; w <<= 1) vsum += __shfl_xor(vsum, w);
    if (lane == 0) red[wid] = vsum;
    __syncthreads();
    if (tid == 0) {
      float t = 0.f;
#pragma unroll
      for (int i = 0; i < 8; ++i) t += red[i];
      atomicAdd(&accum[0], t);   // one atomic per block
    }

  } else {
    // ======================= dispersion =======================
    // block = 16 mu-rows; wave wid (0..7) owns col-eighth [wid*128, +128).
    const int b2 = blockIdx.x;
    bf16x8 a[4];
#pragma unroll
    for (int ks = 0; ks < 4; ++ks) {
      bf16x8 raw = *reinterpret_cast<const bf16x8*>(
          mb + (size_t)(b2 >> 3) * 32768 + (b2 & 7) * 4096 + ks * 1024 + lane * 16);
      bf16x8 s;
#pragma unroll
      for (int e = 0; e < 8; ++e) s[e] = f2bf(bf2f(raw[e]) * K2);
      a[ks] = s;
    }
    int rowg[4];
#pragma unroll
    for (int r = 0; r < 4; ++r) rowg[r] = b2 * 16 + hi * 4 + r;

    float m2[4], s2[4];
#pragma unroll
    for (int r = 0; r < 4; ++r) { m2[r] = -1e30f; s2[r] = 0.f; }

#pragma unroll
    for (int g0 = 0; g0 < 2; ++g0) {
      const int gq = wid * 2 + ((g0 + b2) & 1);   // rotated within the eighth
      const char* gp = mb + gq * 16384 + lane * 16;
      f32x4 acc[4];
#pragma unroll
      for (int f = 0; f < 4; ++f) acc[f] = f32x4{0.f, 0.f, 0.f, 0.f};
#pragma unroll
      for (int f = 0; f < 4; ++f) {
        bf16x8 bq[4];
#pragma unroll
        for (int ks = 0; ks < 4; ++ks)
          bq[ks] = *reinterpret_cast<const bf16x8*>(gp + f * 4096 + ks * 1024);
#pragma unroll
        for (int ks = 0; ks < 4; ++ks)
          acc[f] = __builtin_amdgcn_mfma_f32_16x16x32_bf16(a[ks], bq[ks], acc[f], 0, 0, 0);
      }
#pragma unroll
      for (int r = 0; r < 4; ++r) {
        float l[4];
#pragma unroll
        for (int f = 0; f < 4; ++f) {
          int c = gq * 64 + f * 16 + lo;
          l[f] = (c >= NCLS || c == rowg[r]) ? -1e30f : acc[f][r];
        }
        float cm = fmaxf(fmaxf(l[0], l[1]), fmaxf(l[2], l[3]));
        float mo = m2[r], mn = fmaxf(mo, cm);
        s2[r] = s2[r] * __builtin_amdgcn_exp2f(mo - mn)
              + __builtin_amdgcn_exp2f(l[0] - mn) + __builtin_amdgcn_exp2f(l[1] - mn)
              + __builtin_amdgcn_exp2f(l[2] - mn) + __builtin_amdgcn_exp2f(l[3] - mn);
        m2[r] = mn;
      }
    }

    // per-wave merge over lo; publish per-row partial (m,s) for this eighth
#pragma unroll
    for (int r = 0; r < 4; ++r) {
      float m = m2[r], s = s2[r];
#pragma unroll
      for (int w = 1; w < 16; w <<= 1) {
        float mo = __shfl_xor(m, w), so = __shfl_xor(s, w);
        float mn = fmaxf(m, mo);
        s = s * __builtin_amdgcn_exp2f(m - mn) + so * __builtin_amdgcn_exp2f(mo - mn);
        m = mn;
      }
      if (lo == 0) { dm[wid][hi * 4 + r] = m; dsv[wid][hi * 4 + r] = s; }
    }
    __syncthreads();
    if (wid == 0) {   // all 64 lanes active for the shfl reduce
      float v = 0.f;
      if (lane < 16) {
        float m = -1e30f, s = 0.f;
#pragma unroll
        for (int q = 0; q < 8; ++q) {
          float mq = dm[q][lane], sq = dsv[q][lane];
          float mn = fmaxf(m, mq);
          s = s * __builtin_amdgcn_exp2f(m - mn) + sq * __builtin_amdgcn_exp2f(mq - mn);
          m = mn;
        }
        if (b2 * 16 + lane < NCLS)
          v = m + __builtin_amdgcn_logf(fmaxf(s, 1e-30f));
      }
#pragma unroll
      for (int w = 1; w < 16; w <<= 1) v += __shfl_xor(v, w);
      if (lane == 0) atomicAdd(&accum[1], v);
    }
  }
}

__global__ void finalize_k(const float* __restrict__ accum, float* __restrict__ out) {
  float loss_comp = -(LN2 * accum[0] / (float)NB);
  float loss_dis = logf(1.0f / (float)(NCLS - 1)) + LN2 * accum[1] / (float)NCLS;
  out[0] = loss_dis + 2.0f * loss_comp;
}

extern "C" void kernel_launch(void* const* d_in, const int* in_sizes, int n_in,
                              void* d_out, int out_size, void* d_ws, size_t ws_size,
                              hipStream_t stream) {
  const float* z = (const float*)d_in[0];
  const int* tgt = (const int*)d_in[1];
  const float* mu = (const float*)d_in[2];
  float* out = (float*)d_out;
  char* ws = (char*)d_ws;
  float* accum = (float*)ws;            // 256 B
  short* mubf  = (short*)(ws + 256);    // 256 KB frag-major

  prep_mu<<<dim3(64), dim3(256), 0, stream>>>(mu, mubf, accum);
  cider_main<<<dim3(320), dim3(512), 0, stream>>>(z, mubf, tgt, accum);
  finalize_k<<<dim3(1), dim3(1), 0, stream>>>(accum, out);
}

// Round 13
// 45.804 us; speedup vs baseline: 2.0849x; 1.0135x over previous
//
#include <hip/hip_runtime.h>
#include <math.h>

typedef __attribute__((ext_vector_type(4))) float f32x4;
typedef __attribute__((ext_vector_type(8))) short bf16x8;

#define NCLS  1000
#define DDIM  128
#define NB    65536
#define K2    14.426950408889634f   /* (1/T)*log2(e): base-2 logits */
#define LN2   0.6931471805599453f

__device__ inline short f2bf(float f) {
  union { float f; unsigned u; } x; x.f = f;
  unsigned r = (x.u + 0x7fffu + ((x.u >> 16) & 1u)) >> 16;  // RNE
  return (short)r;
}
__device__ inline float bf2f(short b) {
  union { unsigned u; float f; } x; x.u = ((unsigned)(unsigned short)b) << 16;
  return x.f;
}
__device__ inline void gll16(const void* g, void* l) {
  __builtin_amdgcn_global_load_lds(
      (const __attribute__((address_space(1))) unsigned int*)g,
      (__attribute__((address_space(3))) unsigned int*)l, 16, 0, 0);
}

// mu (f32 1000x128) -> bf16 FRAG-MAJOR, zero-padded to 1024 classes.
// byte(c,ks,khi) = (c>>7)*32768 + ((c>>4)&7)*4096 + ks*1024 + (khi*16+(c&15))*16
// Also zeroes the accumulators (replaces a memset launch).
__global__ __launch_bounds__(256) void prep_mu(const float* __restrict__ mu,
                                               short* __restrict__ mubf,
                                               float* __restrict__ accum) {
  if (blockIdx.x == 0 && threadIdx.x < 8) accum[threadIdx.x] = 0.f;
  int idx = blockIdx.x * 256 + threadIdx.x;   // 64 blocks -> 16384 16B units
  int c = idx >> 4, j = idx & 15;
  int ks = j >> 2, khi = j & 3;
  bf16x8 o = {0, 0, 0, 0, 0, 0, 0, 0};
  if (c < NCLS) {
    const float4* p = reinterpret_cast<const float4*>(mu + (size_t)c * DDIM + ks * 32 + khi * 8);
    float4 u0 = p[0], u1 = p[1];
    o[0] = f2bf(u0.x); o[1] = f2bf(u0.y); o[2] = f2bf(u0.z); o[3] = f2bf(u0.w);
    o[4] = f2bf(u1.x); o[5] = f2bf(u1.y); o[6] = f2bf(u1.z); o[7] = f2bf(u1.w);
  }
  size_t a16 = (size_t)(c >> 7) * 2048 + ((c >> 4) & 7) * 256 + ks * 64 + khi * 16 + (c & 15);
  *reinterpret_cast<bf16x8*>(mubf + a16 * 8) = o;
}

// ONE kernel, grid 320 x 512 threads (8 waves):
//  blocks 0..63   : dispersion (16 mu-rows each; wave wid owns col-eighth)
//  blocks 64..319 : compactness (256 z-rows each = 8 waves x 32 rows).
// Comp: 2x32KB LDS dbuf, 8 phases, 1 barrier/phase, block-rotated chunk order.
// r11: acc ping-pong — softmax of phase p-1's group-1 acc is issued at the
// top of phase p (fills stage-DMA + ds_read latency); softmax(accA)
// interleaves with accB's MFMAs. Breaks the per-wave VALU->MFMA->VALU chain.
__global__ __launch_bounds__(512, 2) void cider_main(
    const float* __restrict__ z, const short* __restrict__ mubf,
    const int* __restrict__ tgt, float* __restrict__ accum) {
  __shared__ __align__(16) char Bt[2][32768];
  __shared__ float red[8];
  __shared__ float dm[8][16], dsv[8][16];

  const int tid = threadIdx.x;
  const int wid = tid >> 6, lane = tid & 63;
  const int lo = lane & 15, hi = lane >> 4;
  const char* mb = (const char*)mubf;

  if (blockIdx.x >= 64) {
    // ======================= compactness =======================
    const int b = blockIdx.x - 64;
    const int rowbase = b * 256 + wid * 32;
    const int rot = b & 7;

    {  // stage phase 0 (chunk rot) into buf 0 — flies under the prologue
      const char* src = mb + rot * 32768 + tid * 16;
      char* dst = &Bt[0][0] + tid * 16;
#pragma unroll
      for (int i = 0; i < 4; ++i) gll16(src + i * 8192, dst + i * 8192);
    }

    // A fragments (scaled by K2) + pos via register dot
    bf16x8 a[2][4];
    float pd[2];
#pragma unroll
    for (int rt = 0; rt < 2; ++rt) {
      int row = rowbase + rt * 16 + lo;
      const float4* zp = reinterpret_cast<const float4*>(z + (size_t)row * DDIM);
#pragma unroll
      for (int ks = 0; ks < 4; ++ks) {
        float4 u0 = zp[ks * 8 + hi * 2];
        float4 u1 = zp[ks * 8 + hi * 2 + 1];
        bf16x8 s;
        s[0] = f2bf(u0.x * K2); s[1] = f2bf(u0.y * K2);
        s[2] = f2bf(u0.z * K2); s[3] = f2bf(u0.w * K2);
        s[4] = f2bf(u1.x * K2); s[5] = f2bf(u1.y * K2);
        s[6] = f2bf(u1.z * K2); s[7] = f2bf(u1.w * K2);
        a[rt][ks] = s;
      }
      int t = tgt[row];
      const char* tp = mb + (size_t)(t >> 7) * 32768 + ((t >> 4) & 7) * 4096 + (t & 15) * 16;
      float ad = 0.f;
#pragma unroll
      for (int ks = 0; ks < 4; ++ks) {
        bf16x8 mv = *reinterpret_cast<const bf16x8*>(tp + ks * 1024 + hi * 256);
#pragma unroll
        for (int e = 0; e < 8; ++e) ad += bf2f(a[rt][ks][e]) * bf2f(mv[e]);
      }
      ad += __shfl_xor(ad, 16);
      ad += __shfl_xor(ad, 32);
      pd[rt] = ad;
    }

    float m2[2][4], s2[2][4];
#pragma unroll
    for (int rt = 0; rt < 2; ++rt)
#pragma unroll
      for (int r = 0; r < 4; ++r) { m2[rt][r] = -1e30f; s2[rt][r] = 0.f; }

    f32x4 accA[2][4], accB[2][4];   // ping-pong, all indices static (rule #20)

    auto domfma = [&](const char* bp, f32x4 (&acc)[2][4]) {
#pragma unroll
      for (int rt = 0; rt < 2; ++rt)
#pragma unroll
        for (int f = 0; f < 4; ++f) acc[rt][f] = f32x4{0.f, 0.f, 0.f, 0.f};
#pragma unroll
      for (int f = 0; f < 4; ++f) {
        bf16x8 bq[4];
#pragma unroll
        for (int ks = 0; ks < 4; ++ks)
          bq[ks] = *reinterpret_cast<const bf16x8*>(bp + f * 4096 + ks * 1024 + lane * 16);
#pragma unroll
        for (int ks = 0; ks < 4; ++ks) {
          acc[0][f] = __builtin_amdgcn_mfma_f32_16x16x32_bf16(a[0][ks], bq[ks], acc[0][f], 0, 0, 0);
          acc[1][f] = __builtin_amdgcn_mfma_f32_16x16x32_bf16(a[1][ks], bq[ks], acc[1][f], 0, 0, 0);
        }
      }
    };
    auto dosm = [&](f32x4 (&acc)[2][4]) {
#pragma unroll
      for (int rt = 0; rt < 2; ++rt)
#pragma unroll
        for (int r = 0; r < 4; ++r) {
          float l0 = acc[rt][0][r], l1 = acc[rt][1][r];
          float l2 = acc[rt][2][r], l3 = acc[rt][3][r];
          float cm = fmaxf(fmaxf(l0, l1), fmaxf(l2, l3));
          float mo = m2[rt][r], mn = fmaxf(mo, cm);
          s2[rt][r] = s2[rt][r] * __builtin_amdgcn_exp2f(mo - mn)
                    + __builtin_amdgcn_exp2f(l0 - mn) + __builtin_amdgcn_exp2f(l1 - mn)
                    + __builtin_amdgcn_exp2f(l2 - mn) + __builtin_amdgcn_exp2f(l3 - mn);
          m2[rt][r] = mn;
        }
    };

#pragma unroll 1
    for (int p = 0; p < 8; ++p) {
      __syncthreads();   // stage(p) landed (barrier drains vmcnt); other buf free
      if (p < 7) {       // issue next 32KB chunk; consumed after the next barrier
        const char* src = mb + ((rot + p + 1) & 7) * 32768 + tid * 16;
        char* dst = &Bt[(p + 1) & 1][0] + tid * 16;
#pragma unroll
        for (int i = 0; i < 4; ++i) gll16(src + i * 8192, dst + i * 8192);
      }
      const char* bp = &Bt[p & 1][0];
      if (p > 0) dosm(accB);          // pending softmax from phase p-1 —
                                      // fills stage-DMA + ds_read latency
      domfma(bp, accA);               // group 0
      domfma(bp + 16384, accB);       // group 1
      dosm(accA);                     // interleaves with accB's MFMAs
    }
    dosm(accB);                       // drain pending group 1 of phase 7

    // merge 16 lo-lanes per row; pad correction; per-wave sum(pos2 - lse2)
    float vsum = 0.f;
#pragma unroll
    for (int rt = 0; rt < 2; ++rt)
#pragma unroll
      for (int r = 0; r < 4; ++r) {
        float m = m2[rt][r], s = s2[rt][r];
#pragma unroll
        for (int w = 1; w < 16; w <<= 1) {
          float mo = __shfl_xor(m, w), so = __shfl_xor(s, w);
          float mn = fmaxf(m, mo);
          s = s * __builtin_amdgcn_exp2f(m - mn) + so * __builtin_amdgcn_exp2f(mo - mn);
          m = mn;
        }
        float posv = __shfl(pd[rt], hi * 4 + r);
        if (lo == 0) {
          s -= 24.0f * __builtin_amdgcn_exp2f(0.0f - m);  // 24 pad cols, logit2==0
          s = fmaxf(s, 1e-30f);
          float lse2 = m + __builtin_amdgcn_logf(s);      // v_log_f32 = log2
          vsum += posv - lse2;
        }
      }
#pragma unroll
    for (int w = 1; w < 64; w <<= 1) vsum += __shfl_xor(vsum, w);
    if (lane == 0) red[wid] = vsum;
    __syncthreads();
    if (tid == 0) {
      float t = 0.f;
#pragma unroll
      for (int i = 0; i < 8; ++i) t += red[i];
      atomicAdd(&accum[0], t);   // one atomic per block
    }

  } else {
    // ======================= dispersion =======================
    // block = 16 mu-rows; wave wid (0..7) owns col-eighth [wid*128, +128).
    const int b2 = blockIdx.x;
    bf16x8 a[4];
#pragma unroll
    for (int ks = 0; ks < 4; ++ks) {
      bf16x8 raw = *reinterpret_cast<const bf16x8*>(
          mb + (size_t)(b2 >> 3) * 32768 + (b2 & 7) * 4096 + ks * 1024 + lane * 16);
      bf16x8 s;
#pragma unroll
      for (int e = 0; e < 8; ++e) s[e] = f2bf(bf2f(raw[e]) * K2);
      a[ks] = s;
    }
    int rowg[4];
#pragma unroll
    for (int r = 0; r < 4; ++r) rowg[r] = b2 * 16 + hi * 4 + r;

    float m2[4], s2[4];
#pragma unroll
    for (int r = 0; r < 4; ++r) { m2[r] = -1e30f; s2[r] = 0.f; }

#pragma unroll
    for (int g0 = 0; g0 < 2; ++g0) {
      const int gq = wid * 2 + ((g0 + b2) & 1);   // rotated within the eighth
      const char* gp = mb + gq * 16384 + lane * 16;
      f32x4 acc[4];
#pragma unroll
      for (int f = 0; f < 4; ++f) acc[f] = f32x4{0.f, 0.f, 0.f, 0.f};
#pragma unroll
      for (int f = 0; f < 4; ++f) {
        bf16x8 bq[4];
#pragma unroll
        for (int ks = 0; ks < 4; ++ks)
          bq[ks] = *reinterpret_cast<const bf16x8*>(gp + f * 4096 + ks * 1024);
#pragma unroll
        for (int ks = 0; ks < 4; ++ks)
          acc[f] = __builtin_amdgcn_mfma_f32_16x16x32_bf16(a[ks], bq[ks], acc[f], 0, 0, 0);
      }
#pragma unroll
      for (int r = 0; r < 4; ++r) {
        float l[4];
#pragma unroll
        for (int f = 0; f < 4; ++f) {
          int c = gq * 64 + f * 16 + lo;
          l[f] = (c >= NCLS || c == rowg[r]) ? -1e30f : acc[f][r];
        }
        float cm = fmaxf(fmaxf(l[0], l[1]), fmaxf(l[2], l[3]));
        float mo = m2[r], mn = fmaxf(mo, cm);
        s2[r] = s2[r] * __builtin_amdgcn_exp2f(mo - mn)
              + __builtin_amdgcn_exp2f(l[0] - mn) + __builtin_amdgcn_exp2f(l[1] - mn)
              + __builtin_amdgcn_exp2f(l[2] - mn) + __builtin_amdgcn_exp2f(l[3] - mn);
        m2[r] = mn;
      }
    }

    // per-wave merge over lo; publish per-row partial (m,s) for this eighth
#pragma unroll
    for (int r = 0; r < 4; ++r) {
      float m = m2[r], s = s2[r];
#pragma unroll
      for (int w = 1; w < 16; w <<= 1) {
        float mo = __shfl_xor(m, w), so = __shfl_xor(s, w);
        float mn = fmaxf(m, mo);
        s = s * __builtin_amdgcn_exp2f(m - mn) + so * __builtin_amdgcn_exp2f(mo - mn);
        m = mn;
      }
      if (lo == 0) { dm[wid][hi * 4 + r] = m; dsv[wid][hi * 4 + r] = s; }
    }
    __syncthreads();
    if (wid == 0) {   // all 64 lanes active for the shfl reduce
      float v = 0.f;
      if (lane < 16) {
        float m = -1e30f, s = 0.f;
#pragma unroll
        for (int q = 0; q < 8; ++q) {
          float mq = dm[q][lane], sq = dsv[q][lane];
          float mn = fmaxf(m, mq);
          s = s * __builtin_amdgcn_exp2f(m - mn) + sq * __builtin_amdgcn_exp2f(mq - mn);
          m = mn;
        }
        if (b2 * 16 + lane < NCLS)
          v = m + __builtin_amdgcn_logf(fmaxf(s, 1e-30f));
      }
#pragma unroll
      for (int w = 1; w < 16; w <<= 1) v += __shfl_xor(v, w);
      if (lane == 0) atomicAdd(&accum[1], v);
    }
  }
}

__global__ void finalize_k(const float* __restrict__ accum, float* __restrict__ out) {
  float loss_comp = -(LN2 * accum[0] / (float)NB);
  float loss_dis = logf(1.0f / (float)(NCLS - 1)) + LN2 * accum[1] / (float)NCLS;
  out[0] = loss_dis + 2.0f * loss_comp;
}

extern "C" void kernel_launch(void* const* d_in, const int* in_sizes, int n_in,
                              void* d_out, int out_size, void* d_ws, size_t ws_size,
                              hipStream_t stream) {
  const float* z = (const float*)d_in[0];
  const int* tgt = (const int*)d_in[1];
  const float* mu = (const float*)d_in[2];
  float* out = (float*)d_out;
  char* ws = (char*)d_ws;
  float* accum = (float*)ws;            // 256 B
  short* mubf  = (short*)(ws + 256);    // 256 KB frag-major

  prep_mu<<<dim3(64), dim3(256), 0, stream>>>(mu, mubf, accum);
  cider_main<<<dim3(320), dim3(512), 0, stream>>>(z, mubf, tgt, accum);
  finalize_k<<<dim3(1), dim3(1), 0, stream>>>(accum, out);
}

// Round 14
// 44.877 us; speedup vs baseline: 2.1280x; 1.0207x over previous
//
#include <hip/hip_runtime.h>
#include <math.h>

typedef __attribute__((ext_vector_type(4))) float f32x4;
typedef __attribute__((ext_vector_type(8))) short bf16x8;

#define NCLS  1000
#define DDIM  128
#define NB    65536
#define K2    14.426950408889634f   /* (1/T)*log2(e): base-2 logits */
#define LN2   0.6931471805599453f

__device__ inline short f2bf(float f) {
  union { float f; unsigned u; } x; x.f = f;
  unsigned r = (x.u + 0x7fffu + ((x.u >> 16) & 1u)) >> 16;  // RNE
  return (short)r;
}
__device__ inline float bf2f(short b) {
  union { unsigned u; float f; } x; x.u = ((unsigned)(unsigned short)b) << 16;
  return x.f;
}

// mu (f32 1000x128) -> bf16 FRAG-MAJOR, zero-padded to 1024 classes.
// byte(c,ks,khi) = (c>>7)*32768 + ((c>>4)&7)*4096 + ks*1024 + (khi*16+(c&15))*16
// Each MFMA B-fragment (16 cols x 32 k) is a contiguous lane-linear 1KB.
// Also zeroes the accumulators (replaces a memset launch).
__global__ __launch_bounds__(256) void prep_mu(const float* __restrict__ mu,
                                               short* __restrict__ mubf,
                                               float* __restrict__ accum) {
  if (blockIdx.x == 0 && threadIdx.x < 8) accum[threadIdx.x] = 0.f;
  int idx = blockIdx.x * 256 + threadIdx.x;   // 64 blocks -> 16384 16B units
  int c = idx >> 4, j = idx & 15;
  int ks = j >> 2, khi = j & 3;
  bf16x8 o = {0, 0, 0, 0, 0, 0, 0, 0};
  if (c < NCLS) {
    const float4* p = reinterpret_cast<const float4*>(mu + (size_t)c * DDIM + ks * 32 + khi * 8);
    float4 u0 = p[0], u1 = p[1];
    o[0] = f2bf(u0.x); o[1] = f2bf(u0.y); o[2] = f2bf(u0.z); o[3] = f2bf(u0.w);
    o[4] = f2bf(u1.x); o[5] = f2bf(u1.y); o[6] = f2bf(u1.z); o[7] = f2bf(u1.w);
  }
  size_t a16 = (size_t)(c >> 7) * 2048 + ((c >> 4) & 7) * 256 + ks * 64 + khi * 16 + (c & 15);
  *reinterpret_cast<bf16x8*>(mubf + a16 * 8) = o;
}

// Grid 576 x 256 threads (4 waves):
//  blocks 0..63   : dispersion (16 mu-rows; wave wid owns a col-quarter)
//  blocks 64..575 : compactness (128 z-rows = 4 waves x 32 rows).
// Comp is BARRIER-FREE and LDS-FREE: B-fragments read from L1/L2 (frag-major
// addresses are wave-identical -> L1 multicast within a block), with explicit
// register double-buffered prefetch (bqA/bqB, 1 group = 16 fragments ahead)
// so L2 latency hides under MFMA+softmax. Group order rotated per block.
__global__ __launch_bounds__(256, 2) void cider_main(
    const float* __restrict__ z, const short* __restrict__ mubf,
    const int* __restrict__ tgt, float* __restrict__ accum) {
  __shared__ float red[4];
  __shared__ float dm[4][16], dsv[4][16];

  const int tid = threadIdx.x;
  const int wid = tid >> 6, lane = tid & 63;
  const int lo = lane & 15, hi = lane >> 4;
  const char* mb = (const char*)mubf;

  if (blockIdx.x >= 64) {
    // ======================= compactness =======================
    const int b = blockIdx.x - 64;                       // 0..511
    const int rowbase = b * 128 + wid * 32;
    const int rot = ((b >> 7) + (b >> 3)) & 15;          // de-hot-spot rotation

    auto gaddr = [&](int g, int j) {   // group g (16KB), fragment j = f*4+ks
      return reinterpret_cast<const bf16x8*>(mb + g * 16384 + j * 1024 + lane * 16);
    };

    bf16x8 bqA[16], bqB[16];
#pragma unroll
    for (int j = 0; j < 16; ++j) bqA[j] = *gaddr(rot, j);   // prefetch group 0

    // A fragments (scaled by K2) + pos via register dot (flies under bqA loads)
    bf16x8 a[2][4];
    float pd[2];
#pragma unroll
    for (int rt = 0; rt < 2; ++rt) {
      int row = rowbase + rt * 16 + lo;
      const float4* zp = reinterpret_cast<const float4*>(z + (size_t)row * DDIM);
#pragma unroll
      for (int ks = 0; ks < 4; ++ks) {
        float4 u0 = zp[ks * 8 + hi * 2];
        float4 u1 = zp[ks * 8 + hi * 2 + 1];
        bf16x8 s;
        s[0] = f2bf(u0.x * K2); s[1] = f2bf(u0.y * K2);
        s[2] = f2bf(u0.z * K2); s[3] = f2bf(u0.w * K2);
        s[4] = f2bf(u1.x * K2); s[5] = f2bf(u1.y * K2);
        s[6] = f2bf(u1.z * K2); s[7] = f2bf(u1.w * K2);
        a[rt][ks] = s;
      }
      int t = tgt[row];
      const char* tp = mb + (size_t)(t >> 7) * 32768 + ((t >> 4) & 7) * 4096 + (t & 15) * 16;
      float ad = 0.f;
#pragma unroll
      for (int ks = 0; ks < 4; ++ks) {
        bf16x8 mv = *reinterpret_cast<const bf16x8*>(tp + ks * 1024 + hi * 256);
#pragma unroll
        for (int e = 0; e < 8; ++e) ad += bf2f(a[rt][ks][e]) * bf2f(mv[e]);
      }
      ad += __shfl_xor(ad, 16);
      ad += __shfl_xor(ad, 32);
      pd[rt] = ad;
    }

    float m2[2][4], s2[2][4];
#pragma unroll
    for (int rt = 0; rt < 2; ++rt)
#pragma unroll
      for (int r = 0; r < 4; ++r) { m2[rt][r] = -1e30f; s2[rt][r] = 0.f; }

    const f32x4 zv = {0.f, 0.f, 0.f, 0.f};   // hoisted zero C-operand

    auto compute = [&](bf16x8 (&cur)[16]) {
      f32x4 acc[2][4];
#pragma unroll
      for (int f = 0; f < 4; ++f) {
        acc[0][f] = __builtin_amdgcn_mfma_f32_16x16x32_bf16(a[0][0], cur[f * 4], zv, 0, 0, 0);
        acc[1][f] = __builtin_amdgcn_mfma_f32_16x16x32_bf16(a[1][0], cur[f * 4], zv, 0, 0, 0);
#pragma unroll
        for (int ks = 1; ks < 4; ++ks) {
          acc[0][f] = __builtin_amdgcn_mfma_f32_16x16x32_bf16(a[0][ks], cur[f * 4 + ks], acc[0][f], 0, 0, 0);
          acc[1][f] = __builtin_amdgcn_mfma_f32_16x16x32_bf16(a[1][ks], cur[f * 4 + ks], acc[1][f], 0, 0, 0);
        }
      }
#pragma unroll
      for (int rt = 0; rt < 2; ++rt)
#pragma unroll
        for (int r = 0; r < 4; ++r) {
          float l0 = acc[rt][0][r], l1 = acc[rt][1][r];
          float l2 = acc[rt][2][r], l3 = acc[rt][3][r];
          float cm = fmaxf(fmaxf(l0, l1), fmaxf(l2, l3));
          float mo = m2[rt][r], mn = fmaxf(mo, cm);
          s2[rt][r] = s2[rt][r] * __builtin_amdgcn_exp2f(mo - mn)
                    + __builtin_amdgcn_exp2f(l0 - mn) + __builtin_amdgcn_exp2f(l1 - mn)
                    + __builtin_amdgcn_exp2f(l2 - mn) + __builtin_amdgcn_exp2f(l3 - mn);
          m2[rt][r] = mn;
        }
    };

#pragma unroll 1
    for (int it = 0; it < 8; ++it) {   // 2 groups per iter, reg-dbuf prefetch
      const int g1 = (rot + 2 * it + 1) & 15;
      const int g2 = (rot + 2 * it + 2) & 15;
#pragma unroll
      for (int j = 0; j < 16; ++j) bqB[j] = *gaddr(g1, j);  // issue early
      compute(bqA);                                         // MFMA+softmax cover
      if (it < 7) {
#pragma unroll
        for (int j = 0; j < 16; ++j) bqA[j] = *gaddr(g2, j);
      }
      compute(bqB);
    }

    // merge 16 lo-lanes per row; pad correction; per-wave sum(pos2 - lse2)
    float vsum = 0.f;
#pragma unroll
    for (int rt = 0; rt < 2; ++rt)
#pragma unroll
      for (int r = 0; r < 4; ++r) {
        float m = m2[rt][r], s = s2[rt][r];
#pragma unroll
        for (int w = 1; w < 16; w <<= 1) {
          float mo = __shfl_xor(m, w), so = __shfl_xor(s, w);
          float mn = fmaxf(m, mo);
          s = s * __builtin_amdgcn_exp2f(m - mn) + so * __builtin_amdgcn_exp2f(mo - mn);
          m = mn;
        }
        float posv = __shfl(pd[rt], hi * 4 + r);
        if (lo == 0) {
          s -= 24.0f * __builtin_amdgcn_exp2f(0.0f - m);  // 24 pad cols, logit2==0
          s = fmaxf(s, 1e-30f);
          float lse2 = m + __builtin_amdgcn_logf(s);      // v_log_f32 = log2
          vsum += posv - lse2;
        }
      }
#pragma unroll
    for (int w = 1; w < 64; w <<= 1) vsum += __shfl_xor(vsum, w);
    if (lane == 0) red[wid] = vsum;
    __syncthreads();
    if (tid == 0)
      atomicAdd(&accum[0], red[0] + red[1] + red[2] + red[3]);

  } else {
    // ======================= dispersion =======================
    // block = 16 mu-rows; wave wid (0..3) owns col-quarter [wid*256, +256).
    const int b2 = blockIdx.x;
    bf16x8 a[4];
#pragma unroll
    for (int ks = 0; ks < 4; ++ks) {
      bf16x8 raw = *reinterpret_cast<const bf16x8*>(
          mb + (size_t)(b2 >> 3) * 32768 + (b2 & 7) * 4096 + ks * 1024 + lane * 16);
      bf16x8 s;
#pragma unroll
      for (int e = 0; e < 8; ++e) s[e] = f2bf(bf2f(raw[e]) * K2);
      a[ks] = s;
    }
    int rowg[4];
#pragma unroll
    for (int r = 0; r < 4; ++r) rowg[r] = b2 * 16 + hi * 4 + r;

    float m2[4], s2[4];
#pragma unroll
    for (int r = 0; r < 4; ++r) { m2[r] = -1e30f; s2[r] = 0.f; }

#pragma unroll
    for (int g0 = 0; g0 < 4; ++g0) {
      const int gq = wid * 4 + ((g0 + b2) & 3);   // rotated within the quarter
      const char* gp = mb + gq * 16384 + lane * 16;
      f32x4 acc[4];
#pragma unroll
      for (int f = 0; f < 4; ++f) acc[f] = f32x4{0.f, 0.f, 0.f, 0.f};
#pragma unroll
      for (int f = 0; f < 4; ++f) {
        bf16x8 bq[4];
#pragma unroll
        for (int ks = 0; ks < 4; ++ks)
          bq[ks] = *reinterpret_cast<const bf16x8*>(gp + f * 4096 + ks * 1024);
#pragma unroll
        for (int ks = 0; ks < 4; ++ks)
          acc[f] = __builtin_amdgcn_mfma_f32_16x16x32_bf16(a[ks], bq[ks], acc[f], 0, 0, 0);
      }
#pragma unroll
      for (int r = 0; r < 4; ++r) {
        float l[4];
#pragma unroll
        for (int f = 0; f < 4; ++f) {
          int c = gq * 64 + f * 16 + lo;
          l[f] = (c >= NCLS || c == rowg[r]) ? -1e30f : acc[f][r];
        }
        float cm = fmaxf(fmaxf(l[0], l[1]), fmaxf(l[2], l[3]));
        float mo = m2[r], mn = fmaxf(mo, cm);
        s2[r] = s2[r] * __builtin_amdgcn_exp2f(mo - mn)
              + __builtin_amdgcn_exp2f(l[0] - mn) + __builtin_amdgcn_exp2f(l[1] - mn)
              + __builtin_amdgcn_exp2f(l[2] - mn) + __builtin_amdgcn_exp2f(l[3] - mn);
        m2[r] = mn;
      }
    }

    // per-wave merge over lo; publish per-row partial (m,s) for this quarter
#pragma unroll
    for (int r = 0; r < 4; ++r) {
      float m = m2[r], s = s2[r];
#pragma unroll
      for (int w = 1; w < 16; w <<= 1) {
        float mo = __shfl_xor(m, w), so = __shfl_xor(s, w);
        float mn = fmaxf(m, mo);
        s = s * __builtin_amdgcn_exp2f(m - mn) + so * __builtin_amdgcn_exp2f(mo - mn);
        m = mn;
      }
      if (lo == 0) { dm[wid][hi * 4 + r] = m; dsv[wid][hi * 4 + r] = s; }
    }
    __syncthreads();
    if (wid == 0) {   // all 64 lanes active for the shfl reduce
      float v = 0.f;
      if (lane < 16) {
        float m = -1e30f, s = 0.f;
#pragma unroll
        for (int q = 0; q < 4; ++q) {
          float mq = dm[q][lane], sq = dsv[q][lane];
          float mn = fmaxf(m, mq);
          s = s * __builtin_amdgcn_exp2f(m - mn) + sq * __builtin_amdgcn_exp2f(mq - mn);
          m = mn;
        }
        if (b2 * 16 + lane < NCLS)
          v = m + __builtin_amdgcn_logf(fmaxf(s, 1e-30f));
      }
#pragma unroll
      for (int w = 1; w < 16; w <<= 1) v += __shfl_xor(v, w);
      if (lane == 0) atomicAdd(&accum[1], v);
    }
  }
}

__global__ void finalize_k(const float* __restrict__ accum, float* __restrict__ out) {
  float loss_comp = -(LN2 * accum[0] / (float)NB);
  float loss_dis = logf(1.0f / (float)(NCLS - 1)) + LN2 * accum[1] / (float)NCLS;
  out[0] = loss_dis + 2.0f * loss_comp;
}

extern "C" void kernel_launch(void* const* d_in, const int* in_sizes, int n_in,
                              void* d_out, int out_size, void* d_ws, size_t ws_size,
                              hipStream_t stream) {
  const float* z = (const float*)d_in[0];
  const int* tgt = (const int*)d_in[1];
  const float* mu = (const float*)d_in[2];
  float* out = (float*)d_out;
  char* ws = (char*)d_ws;
  float* accum = (float*)ws;            // 256 B
  short* mubf  = (short*)(ws + 256);    // 256 KB frag-major

  prep_mu<<<dim3(64), dim3(256), 0, stream>>>(mu, mubf, accum);
  cider_main<<<dim3(576), dim3(256), 0, stream>>>(z, mubf, tgt, accum);
  finalize_k<<<dim3(1), dim3(1), 0, stream>>>(accum, out);
}